// Round 1
// baseline (631.035 us; speedup 1.0000x reference)
//
#include <hip/hip_runtime.h>
#include <hip/hip_bf16.h>

// Problem constants
#define S_LEN 2048
#define HID 4096
#define NH 32
#define NKV 8
#define HD 128
#define LDQKV 6144   // fused QKV output: cols [0,4096)=Q, [4096,5120)=K, [5120,6144)=V

typedef __bf16 bf16x8 __attribute__((ext_vector_type(8)));
typedef __bf16 bf16x4 __attribute__((ext_vector_type(4)));
typedef float f32x4 __attribute__((ext_vector_type(4)));

// async global->LDS, 16B per lane (HW: wave-uniform LDS base + lane*16)
#define GLD16(gp, lp)                                                                   \
    __builtin_amdgcn_global_load_lds((const __attribute__((address_space(1))) void*)(gp), \
                                     (__attribute__((address_space(3))) void*)(lp), 16, 0, 0)

// ---------------------------------------------------------------------------
__global__ void cast_bf16_kernel(const float* __restrict__ x, __bf16* __restrict__ y, int n) {
    int i = (blockIdx.x * blockDim.x + threadIdx.x) * 4;
    if (i < n) {
        float4 v = *reinterpret_cast<const float4*>(x + i);
        bf16x4 o;
        o.x = (__bf16)v.x; o.y = (__bf16)v.y; o.z = (__bf16)v.z; o.w = (__bf16)v.w;
        *reinterpret_cast<bf16x4*>(y + i) = o;
    }
}

// ---------------------------------------------------------------------------
// transpose + cast + scale: W [K][N] fp32 -> WT [N][K] bf16 * scale
// ---------------------------------------------------------------------------
__global__ void transpose_cast_kernel(const float* __restrict__ W, __bf16* __restrict__ WT,
                                      int K, int N, float scale) {
    __shared__ float tile[32][33];
    int bx = blockIdx.x;  // over N/32
    int by = blockIdx.y;  // over K/32
    int tx = threadIdx.x; // 32
    int ty = threadIdx.y; // 8
    int n = bx * 32 + tx;
#pragma unroll
    for (int i = 0; i < 4; i++) {
        int k = by * 32 + ty + i * 8;
        tile[ty + i * 8][tx] = W[(size_t)k * N + n];
    }
    __syncthreads();
    int k2 = by * 32 + tx;
#pragma unroll
    for (int i = 0; i < 4; i++) {
        int n2 = bx * 32 + ty + i * 8;
        WT[(size_t)n2 * K + k2] = (__bf16)(tile[tx][ty + i * 8] * scale);
    }
}

// ---------------------------------------------------------------------------
// strided bf16 transpose: V [R][C] (ld=ldin) -> VT [C][R] (ld=ldout)
// ---------------------------------------------------------------------------
__global__ void transpose_bf16_kernel(const __bf16* __restrict__ V, int ldin,
                                      __bf16* __restrict__ VT, int ldout) {
    __shared__ __bf16 tile[32][33];
    int bx = blockIdx.x;
    int by = blockIdx.y;
    int tx = threadIdx.x;
    int ty = threadIdx.y;
#pragma unroll
    for (int i = 0; i < 4; i++)
        tile[ty + i * 8][tx] = V[(size_t)(by * 32 + ty + i * 8) * ldin + bx * 32 + tx];
    __syncthreads();
#pragma unroll
    for (int i = 0; i < 4; i++)
        VT[(size_t)(bx * 32 + ty + i * 8) * ldout + by * 32 + tx] = tile[tx][ty + i * 8];
}

// ---------------------------------------------------------------------------
// 256x256 8-phase NT GEMM (m201-style template): C = A[M,K] * BT[N,K]^T.
// 512 threads = 8 waves (2M x 4N), per-wave 128x64 output, BK=64, 128 KiB LDS.
// T2: source-side XOR swizzle (slot ^= row&7) -> conflict-free ds_read_b128.
// T3/T4: counted vmcnt(8) at tile boundaries only -- next tile's 8 staging
//        loads stay in flight across the barrier; never drains mid-loop.
// T5: s_setprio(1) around each 16-MFMA quadrant cluster.
// Pipeline proof: tile t+2 is staged into buf[t&1] only after the last
// phase-barrier of tile t (all waves done reading it); vmcnt(8) then retires
// exactly tile t+1's 8 loads (issued one full 4-phase tile earlier).
// ---------------------------------------------------------------------------
template <int MQ, int NQ>
__device__ __forceinline__ void gemm_phase(const __bf16* __restrict__ Asb,
                                           const __bf16* __restrict__ Bsb,
                                           f32x4 (&acc)[8][4], int wm, int wn,
                                           int quad, int l16) {
    bf16x8 af[2][4], bfr[2][2];
#pragma unroll
    for (int kk = 0; kk < 2; kk++) {
        int slot = (kk * 4 + quad) ^ (l16 & 7);
#pragma unroll
        for (int i = 0; i < 4; i++) {
            int row = wm + (MQ * 4 + i) * 16 + l16;
            af[kk][i] = *reinterpret_cast<const bf16x8*>(&Asb[row * 64 + slot * 8]);
        }
#pragma unroll
        for (int j = 0; j < 2; j++) {
            int row = wn + (NQ * 2 + j) * 16 + l16;
            bfr[kk][j] = *reinterpret_cast<const bf16x8*>(&Bsb[row * 64 + slot * 8]);
        }
    }
    __builtin_amdgcn_s_barrier();
    asm volatile("s_waitcnt lgkmcnt(0)" ::: "memory");
    __builtin_amdgcn_s_setprio(1);
#pragma unroll
    for (int kk = 0; kk < 2; kk++)
#pragma unroll
        for (int i = 0; i < 4; i++)
#pragma unroll
            for (int j = 0; j < 2; j++)
                acc[MQ * 4 + i][NQ * 2 + j] = __builtin_amdgcn_mfma_f32_16x16x32_bf16(
                    af[kk][i], bfr[kk][j], acc[MQ * 4 + i][NQ * 2 + j], 0, 0, 0);
    __builtin_amdgcn_s_setprio(0);
    __builtin_amdgcn_s_barrier();
}

template <typename OUT_T>
__global__ __launch_bounds__(512, 1) void gemm_bt256_kernel(const __bf16* __restrict__ A, int lda,
                                                            const __bf16* __restrict__ BT, int ldb,
                                                            OUT_T* __restrict__ C, int ldc, int K) {
    __shared__ __bf16 As[2][256 * 64];  // 32 KiB per buffer
    __shared__ __bf16 Bs[2][256 * 64];  // total 128 KiB
    const int n0 = blockIdx.x * 256;
    const int m0 = blockIdx.y * 256;
    const int tid = threadIdx.x;
    const int wave = tid >> 6, lane = tid & 63, quad = lane >> 4, l16 = lane & 15;
    const int wm = (wave >> 2) * 128;  // 2 M-waves
    const int wn = (wave & 3) * 64;    // 4 N-waves

    f32x4 acc[8][4] = {};

    // stage full 256x64 A + B tiles into buffer b: 8 GLD16 per thread.
    // chunk c -> LDS linear (row = c>>3, slot = c&7); global source column is
    // pre-swizzled (slot ^ row&7) so the swizzled ds_read sees logical order.
    auto STAGE = [&](int b, int kb) {
#pragma unroll
        for (int i = 0; i < 4; i++) {
            int c = i * 512 + tid;
            int row = c >> 3;
            int col8 = (c & 7) ^ (row & 7);
            GLD16(&A[(size_t)(m0 + row) * lda + kb + col8 * 8], &As[b][c * 8]);
            GLD16(&BT[(size_t)(n0 + row) * ldb + kb + col8 * 8], &Bs[b][c * 8]);
        }
    };

    const int nk = K >> 6;
    STAGE(0, 0);
    if (nk > 1) {
        STAGE(1, 64);
        asm volatile("s_waitcnt vmcnt(8)" ::: "memory");  // tile 0 landed; tile 1 in flight
    } else {
        asm volatile("s_waitcnt vmcnt(0)" ::: "memory");
    }
    __builtin_amdgcn_s_barrier();

    for (int kt = 0; kt < nk; ++kt) {
        const int cur = kt & 1;
        const __bf16* Asb = As[cur];
        const __bf16* Bsb = Bs[cur];
        gemm_phase<0, 0>(Asb, Bsb, acc, wm, wn, quad, l16);
        gemm_phase<0, 1>(Asb, Bsb, acc, wm, wn, quad, l16);
        gemm_phase<1, 0>(Asb, Bsb, acc, wm, wn, quad, l16);
        gemm_phase<1, 1>(Asb, Bsb, acc, wm, wn, quad, l16);
        // boundary: buf[cur] fully consumed (last phase barrier above).
        if (kt + 2 < nk) {
            STAGE(cur, (kt + 2) << 6);                        // refill freed buffer
            asm volatile("s_waitcnt vmcnt(8)" ::: "memory");  // tile kt+1 landed
        } else {
            asm volatile("s_waitcnt vmcnt(0)" ::: "memory");  // pipeline tail
        }
        __builtin_amdgcn_s_barrier();
    }

#pragma unroll
    for (int mt = 0; mt < 8; mt++)
#pragma unroll
        for (int nt = 0; nt < 4; nt++)
#pragma unroll
            for (int r = 0; r < 4; r++) {
                int row = m0 + wm + mt * 16 + quad * 4 + r;
                int col = n0 + wn + nt * 16 + l16;
                C[(size_t)row * ldc + col] = (OUT_T)acc[mt][nt][r];
            }
}

// ---------------------------------------------------------------------------
// Flash attention v7 (causal, GQA) — shift-free softmax + MFMA row-sums,
// 2 q-heads per block (K/V staged once serve both), split-KV CS=16.
// Block = (chunk-slot x, head-pair hp). 4 waves x 16 q-rows of a 64-row tile.
// Scores arrive pre-scaled in exp2 domain (scale*log2e folded into Wq), so
// softmax is just exp2 + bf16 store; l comes from mfma(P, ones) — zero
// cross-lane ops. qt<16: direct normalized output. qt>=16: two chunks write
// (O_unnorm bf16, l fp32) partials; combine does (O0+O1)/(l0+l1).
// ---------------------------------------------------------------------------
__global__ __launch_bounds__(256) void attn_kernel(const __bf16* __restrict__ QKV,
                                                   const __bf16* __restrict__ VT,
                                                   __bf16* __restrict__ Ao,
                                                   __bf16* __restrict__ Opart,
                                                   float* __restrict__ Lp) {
    __shared__ __bf16 Ks[64 * 128];      // K tile [64 kv][128 d], chunk-swizzled
    __shared__ __bf16 Vs[128 * 64];      // V^T tile [128 d][64 kv], chunk-swizzled
    __shared__ __bf16 Pl[4][2][16 * 72]; // per-wave, per-head P buffer (+8 pad)
    int x = blockIdx.x;                  // chunk-slot, heavy-first mapping
    int qt, c;
    if (x < 32) { qt = 31 - (x >> 1); c = x & 1; }   // qt 16..31, 2 chunks
    else        { qt = 47 - x;        c = 0;     }   // qt 15..0, 1 chunk
    int hp = blockIdx.y;                 // head pair 0..15
    int kvh = hp >> 1;
    int h0 = kvh * 4 + (hp & 1) * 2;     // absolute heads h0, h0+1
    int t0 = c ? 16 : 0;
    int t1 = c ? qt : min(qt, 15);
    int tid = threadIdx.x;
    int wave = tid >> 6, lane = tid & 63, quad = lane >> 4, l16 = lane & 15;
    int wq = qt * 64 + wave * 16;        // this wave's 16 q-rows
    const __bf16* Kb = QKV + HID + (size_t)kvh * HD;
    const __bf16* Vt = VT + (size_t)kvh * HD * S_LEN;

    // Q fragments for both heads (pre-scaled by scale*log2e via Wq)
    bf16x8 qf[2][4];
#pragma unroll
    for (int h = 0; h < 2; h++)
#pragma unroll
        for (int ks = 0; ks < 4; ks++)
            qf[h][ks] = *reinterpret_cast<const bf16x8*>(
                &QKV[(size_t)(wq + l16) * LDQKV + (h0 + h) * HD + ks * 32 + quad * 8]);

    bf16x8 ones;
#pragma unroll
    for (int j = 0; j < 8; j++) ones[j] = (__bf16)1.0f;

    f32x4 acc_o[2][8] = {};
    f32x4 lacc[2] = {};

    for (int t = t0; t <= t1; t++) {
        int kv0 = t << 6;
        bool diag = (t == qt);
        __syncthreads();  // previous tile's LDS reads done
        // ---- stage K tile: 1024 chunks of 16B, source-side XOR swizzle
#pragma unroll
        for (int i = 0; i < 4; i++) {
            int cc = i * 256 + tid;
            int row = cc >> 4, sub = cc & 15;
            int col8 = sub ^ (row & 15);
            GLD16(&Kb[(size_t)(kv0 + row) * LDQKV + col8 * 8], &Ks[cc * 8]);
        }
        // ---- stage V^T tile: 1024 chunks of 16B
#pragma unroll
        for (int i = 0; i < 4; i++) {
            int cc = i * 256 + tid;
            int row = cc >> 3, sub = cc & 7;
            int col8 = sub ^ (row & 7);
            GLD16(&Vt[(size_t)row * S_LEN + kv0 + col8 * 8], &Vs[cc * 8]);
        }
        __syncthreads();  // drains vmcnt + barrier

        // ---- S = Q K^T for both heads (kf shared)
        f32x4 sacc[2][4] = {};
#pragma unroll
        for (int ks = 0; ks < 4; ks++) {
            bf16x8 kf[4];
#pragma unroll
            for (int n = 0; n < 4; n++) {
                int row = n * 16 + l16;
                int sub = (ks * 4 + quad) ^ l16;
                kf[n] = *reinterpret_cast<const bf16x8*>(&Ks[row * 128 + sub * 8]);
            }
#pragma unroll
            for (int n = 0; n < 4; n++) {
                sacc[0][n] = __builtin_amdgcn_mfma_f32_16x16x32_bf16(qf[0][ks], kf[n],
                                                                     sacc[0][n], 0, 0, 0);
                sacc[1][n] = __builtin_amdgcn_mfma_f32_16x16x32_bf16(qf[1][ks], kf[n],
                                                                     sacc[1][n], 0, 0, 0);
            }
        }
        // ---- shift-free softmax: P = exp2(S); no reductions at all
#pragma unroll
        for (int h = 0; h < 2; h++) {
            __bf16* Pw = Pl[wave][h];
#pragma unroll
            for (int r = 0; r < 4; r++) {
                int row = wq + quad * 4 + r;
#pragma unroll
                for (int n = 0; n < 4; n++) {
                    float v = sacc[h][n][r];
                    if (diag) {
                        int col = kv0 + n * 16 + l16;
                        if (col > row) v = -1e30f;  // causal mask (diag tile only)
                    }
                    Pw[(quad * 4 + r) * 72 + n * 16 + l16] =
                        (__bf16)__builtin_amdgcn_exp2f(v);
                }
            }
        }
        // ---- O += P V ; l += P * ones (row-sums via MFMA, lands in all lanes)
#pragma unroll
        for (int ks = 0; ks < 2; ks++) {
            bf16x8 pf0 = *reinterpret_cast<const bf16x8*>(
                &Pl[wave][0][l16 * 72 + ks * 32 + quad * 8]);
            bf16x8 pf1 = *reinterpret_cast<const bf16x8*>(
                &Pl[wave][1][l16 * 72 + ks * 32 + quad * 8]);
            lacc[0] = __builtin_amdgcn_mfma_f32_16x16x32_bf16(pf0, ones, lacc[0], 0, 0, 0);
            lacc[1] = __builtin_amdgcn_mfma_f32_16x16x32_bf16(pf1, ones, lacc[1], 0, 0, 0);
#pragma unroll
            for (int dn = 0; dn < 8; dn++) {
                int row = dn * 16 + l16;
                int sub = (ks * 4 + quad) ^ (row & 7);
                bf16x8 vf = *reinterpret_cast<const bf16x8*>(&Vs[row * 64 + sub * 8]);
                acc_o[0][dn] = __builtin_amdgcn_mfma_f32_16x16x32_bf16(pf0, vf,
                                                                       acc_o[0][dn], 0, 0, 0);
                acc_o[1][dn] = __builtin_amdgcn_mfma_f32_16x16x32_bf16(pf1, vf,
                                                                       acc_o[1][dn], 0, 0, 0);
            }
        }
    }

    // ---- epilogue
    if (qt < 16) {
        // single chunk: normalized output
#pragma unroll
        for (int h = 0; h < 2; h++) {
            float rl[4];
#pragma unroll
            for (int r = 0; r < 4; r++) rl[r] = 1.0f / lacc[h][r];
#pragma unroll
            for (int dn = 0; dn < 8; dn++)
#pragma unroll
                for (int r = 0; r < 4; r++) {
                    int row = wq + quad * 4 + r;
                    int col = (h0 + h) * HD + dn * 16 + l16;
                    Ao[(size_t)row * HID + col] = (__bf16)(acc_o[h][dn][r] * rl[r]);
                }
        }
    } else {
        // two-chunk qt: write unnormalized O + l partials
        int s = (qt - 16) * 2 + c;
#pragma unroll
        for (int h = 0; h < 2; h++) {
            size_t base = ((size_t)(h0 + h) * 32 + s) * 64 + wave * 16;
#pragma unroll
            for (int dn = 0; dn < 8; dn++)
#pragma unroll
                for (int r = 0; r < 4; r++)
                    Opart[(base + quad * 4 + r) * 128 + dn * 16 + l16] =
                        (__bf16)acc_o[h][dn][r];
            if (l16 == 0) {
#pragma unroll
                for (int r = 0; r < 4; r++)
                    Lp[base + quad * 4 + r] = lacc[h][r];
            }
        }
    }
}

// ---------------------------------------------------------------------------
// combine two chunks (qt >= 16): O = (O0 + O1) / (l0 + l1). Shift-free, no exp.
// ---------------------------------------------------------------------------
__global__ __launch_bounds__(256) void attn_combine(const __bf16* __restrict__ Opart,
                                                    const float* __restrict__ Lp,
                                                    __bf16* __restrict__ Ao) {
    int qt = 16 + (int)blockIdx.x;  // 16..31
    int h = blockIdx.y;
    int tid = threadIdx.x;
    size_t b0 = ((size_t)h * 32 + (qt - 16) * 2) * 64;
    size_t b1 = b0 + 64;
#pragma unroll 4
    for (int i = 0; i < 32; i++) {
        int el = i * 256 + tid;
        int rl = el >> 7, col = el & 127;
        float l = Lp[b0 + rl] + Lp[b1 + rl];
        float O = (float)Opart[(b0 + rl) * 128 + col] + (float)Opart[(b1 + rl) * 128 + col];
        int row = qt * 64 + rl;
        Ao[(size_t)row * HID + h * HD + col] = (__bf16)(O / l);
    }
}

// ---------------------------------------------------------------------------
extern "C" void kernel_launch(void* const* d_in, const int* in_sizes, int n_in,
                              void* d_out, int out_size, void* d_ws, size_t ws_size,
                              hipStream_t stream) {
    const float* hs = (const float*)d_in[0];
    // d_in[1] = attention_mask (pure causal; applied analytically)
    const float* wq = (const float*)d_in[2];
    const float* wk = (const float*)d_in[3];
    const float* wv = (const float*)d_in[4];
    const float* wo = (const float*)d_in[5];
    float* out = (float*)d_out;

    char* ws = (char*)d_ws;
    // workspace (92 MB with reuse)
    __bf16* WqkvT = (__bf16*)(ws + (size_t)0);          // 48 MB [6144][4096]; reused for WoT
    __bf16* Opart = (__bf16*)(ws + (size_t)0);          // 17 MB attn partials (weight window,
    float*  Lp    = (float*)(ws + ((size_t)20 << 20));  // 0.3 MB  dead during attention)
    __bf16* Xb    = (__bf16*)(ws + ((size_t)48 << 20)); // 16 MB [2048][4096]; reused for attn out
    __bf16* QKV   = (__bf16*)(ws + ((size_t)64 << 20)); // 24 MB [2048][6144]
    __bf16* VTg   = (__bf16*)(ws + ((size_t)88 << 20)); //  4 MB [1024][2048]
    __bf16* Ab    = Xb;

    const int nX = S_LEN * HID;  // 8M
    const float SC2 = 0.12751743f;  // (1/sqrt(128)) * log2(e), folded into Wq

    // 1) cast hidden to bf16
    cast_bf16_kernel<<<nX / 4 / 256, 256, 0, stream>>>(hs, Xb, nX);
    // 2) fused W_{q,k,v}^T (Wq pre-scaled into exp2 domain)
    transpose_cast_kernel<<<dim3(128, 128), dim3(32, 8), 0, stream>>>(wq, WqkvT, HID, HID, SC2);
    transpose_cast_kernel<<<dim3(32, 128), dim3(32, 8), 0, stream>>>(
        wk, WqkvT + (size_t)4096 * HID, HID, NKV * HD, 1.0f);
    transpose_cast_kernel<<<dim3(32, 128), dim3(32, 8), 0, stream>>>(
        wv, WqkvT + (size_t)5120 * HID, HID, NKV * HD, 1.0f);
    // 3) one fused QKV GEMM: [2048][6144] via 256x256 8-phase kernel
    gemm_bt256_kernel<__bf16><<<dim3(LDQKV / 256, S_LEN / 256), 512, 0, stream>>>(
        Xb, HID, WqkvT, HID, QKV, LDQKV, HID);
    // 4) V^T for PV B-operand (V = QKV cols 5120..6143)
    transpose_bf16_kernel<<<dim3(32, 64), dim3(32, 8), 0, stream>>>(
        QKV + 5120, LDQKV, VTg, S_LEN);
    // 5) flash attention (2-head blocks, shift-free softmax, split-KV) + combine
    attn_kernel<<<dim3(48, 16), 256, 0, stream>>>(QKV, VTg, Ab, Opart, Lp);
    attn_combine<<<dim3(16, 32), 256, 0, stream>>>(Opart, Lp, Ab);
    // 6) out = Ab @ WoT^T (fp32). WoT reuses WqkvT space (partials dead now).
    transpose_cast_kernel<<<dim3(128, 128), dim3(32, 8), 0, stream>>>(wo, WqkvT, HID, HID, 1.0f);
    gemm_bt256_kernel<float><<<dim3(HID / 256, S_LEN / 256), 512, 0, stream>>>(
        Ab, HID, WqkvT, HID, out, HID, HID);
}

// Round 2
// 537.420 us; speedup vs baseline: 1.1742x; 1.1742x over previous
//
#include <hip/hip_runtime.h>
#include <hip/hip_bf16.h>

// Problem constants
#define S_LEN 2048
#define HID 4096
#define NH 32
#define NKV 8
#define HD 128
#define LDQKV 6144   // fused QKV output: cols [0,4096)=Q, [4096,5120)=K, [5120,6144)=V

typedef __bf16 bf16x8 __attribute__((ext_vector_type(8)));
typedef __bf16 bf16x4 __attribute__((ext_vector_type(4)));
typedef float f32x4 __attribute__((ext_vector_type(4)));

// async global->LDS, 16B per lane (HW: wave-uniform LDS base + lane*16)
#define GLD16(gp, lp)                                                                   \
    __builtin_amdgcn_global_load_lds((const __attribute__((address_space(1))) void*)(gp), \
                                     (__attribute__((address_space(3))) void*)(lp), 16, 0, 0)

#define MFMA_BF16(a, b, c) __builtin_amdgcn_mfma_f32_16x16x32_bf16((a), (b), (c), 0, 0, 0)

// ---------------------------------------------------------------------------
__global__ void cast_bf16_kernel(const float* __restrict__ x, __bf16* __restrict__ y, int n) {
    int i = (blockIdx.x * blockDim.x + threadIdx.x) * 4;
    if (i < n) {
        float4 v = *reinterpret_cast<const float4*>(x + i);
        bf16x4 o;
        o.x = (__bf16)v.x; o.y = (__bf16)v.y; o.z = (__bf16)v.z; o.w = (__bf16)v.w;
        *reinterpret_cast<bf16x4*>(y + i) = o;
    }
}

// ---------------------------------------------------------------------------
// transpose + cast + scale: W [K][N] fp32 -> WT [N][K] bf16 * scale
// ---------------------------------------------------------------------------
__global__ void transpose_cast_kernel(const float* __restrict__ W, __bf16* __restrict__ WT,
                                      int K, int N, float scale) {
    __shared__ float tile[32][33];
    int bx = blockIdx.x;  // over N/32
    int by = blockIdx.y;  // over K/32
    int tx = threadIdx.x; // 32
    int ty = threadIdx.y; // 8
    int n = bx * 32 + tx;
#pragma unroll
    for (int i = 0; i < 4; i++) {
        int k = by * 32 + ty + i * 8;
        tile[ty + i * 8][tx] = W[(size_t)k * N + n];
    }
    __syncthreads();
    int k2 = by * 32 + tx;
#pragma unroll
    for (int i = 0; i < 4; i++) {
        int n2 = bx * 32 + ty + i * 8;
        WT[(size_t)n2 * K + k2] = (__bf16)(tile[tx][ty + i * 8] * scale);
    }
}

// ---------------------------------------------------------------------------
// strided bf16 transpose: V [R][C] (ld=ldin) -> VT [C][R] (ld=ldout)
// ---------------------------------------------------------------------------
__global__ void transpose_bf16_kernel(const __bf16* __restrict__ V, int ldin,
                                      __bf16* __restrict__ VT, int ldout) {
    __shared__ __bf16 tile[32][33];
    int bx = blockIdx.x;
    int by = blockIdx.y;
    int tx = threadIdx.x;
    int ty = threadIdx.y;
#pragma unroll
    for (int i = 0; i < 4; i++)
        tile[ty + i * 8][tx] = V[(size_t)(by * 32 + ty + i * 8) * ldin + bx * 32 + tx];
    __syncthreads();
#pragma unroll
    for (int i = 0; i < 4; i++)
        VT[(size_t)(bx * 32 + ty + i * 8) * ldout + by * 32 + tx] = tile[tx][ty + i * 8];
}

// ---------------------------------------------------------------------------
// NT GEMM (m97 structure, 128x128): known-good; used for the out projection
// where grid = 32x16 = 512 blocks keeps all CUs busy.
// ---------------------------------------------------------------------------
template <typename OUT_T>
__global__ __launch_bounds__(256) void gemm_bt_kernel(const __bf16* __restrict__ A, int lda,
                                                      const __bf16* __restrict__ BT, int ldb,
                                                      OUT_T* __restrict__ C, int ldc, int K) {
    __shared__ __bf16 As[128 * 32];
    __shared__ __bf16 Bs[128 * 32];
    int n0 = blockIdx.x * 128;
    int m0 = blockIdx.y * 128;
    int tid = threadIdx.x;
    int wave = tid >> 6, lane = tid & 63, quad = lane >> 4, l16 = lane & 15;
    int wm = (wave >> 1) * 64, wn = (wave & 1) * 64;
    int j0 = wave * 128 + lane;

    f32x4 acc[4][4] = {};

    for (int kb = 0; kb < K; kb += 32) {
        __syncthreads();
#pragma unroll
        for (int q = 0; q < 2; q++) {
            int j = j0 + q * 64;
            int row = j >> 2, col8 = (j & 3) * 8;
            GLD16(&A[(size_t)(m0 + row) * lda + kb + col8], &As[j * 8]);
            GLD16(&BT[(size_t)(n0 + row) * ldb + kb + col8], &Bs[j * 8]);
        }
        __syncthreads();
        bf16x8 af[4], bfr[4];
#pragma unroll
        for (int mt = 0; mt < 4; mt++)
            af[mt] = *reinterpret_cast<const bf16x8*>(&As[(wm + mt * 16 + l16) * 32 + quad * 8]);
#pragma unroll
        for (int nt = 0; nt < 4; nt++)
            bfr[nt] = *reinterpret_cast<const bf16x8*>(&Bs[(wn + nt * 16 + l16) * 32 + quad * 8]);
#pragma unroll
        for (int mt = 0; mt < 4; mt++)
#pragma unroll
            for (int nt = 0; nt < 4; nt++)
                acc[mt][nt] = MFMA_BF16(af[mt], bfr[nt], acc[mt][nt]);
    }

#pragma unroll
    for (int mt = 0; mt < 4; mt++)
#pragma unroll
        for (int nt = 0; nt < 4; nt++)
#pragma unroll
            for (int r = 0; r < 4; r++) {
                int row = m0 + wm + mt * 16 + quad * 4 + r;
                int col = n0 + wn + nt * 16 + l16;
                C[(size_t)row * ldc + col] = (OUT_T)acc[mt][nt][r];
            }
}

// ---------------------------------------------------------------------------
// 256x256 8-phase NT GEMM, register-reuse quadrant schedule (m201 pattern).
// 512 threads = 8 waves; per-wave 128x64 output (frag remap below), BK=64.
// 24 ds_read_b128 / K-tile / wave (minimum): P1 reads A-lo(8)+B-lo(4),
// P2 reads B-hi(4) [A-lo reused], P3 reads A-hi(8) [B-hi reused], P4 reads 0
// [A-hi + B-lo reused]. Fragment remap makes each phase's LDS consumption a
// contiguous 64-row multiple:
//   wave g=(wave>>2): A rows [64g,64g+64) (P1) and +128 (P3)
//   wave w=(wave&3):  B rows [32w,32w+32) (P1) and +128 (P2)
// so P1 consumes A rows 0-127 & B rows 0-127; P2 consumes B rows 128-255;
// P3 consumes A rows 128-255. Staging of tile kt+2 refills the live buffer's
// consumed regions: P2 stages A rows 0-127, P3 stages B rows 0-127, P4 stages
// A+B rows 128-255 — each fenced by the consuming phase's end barrier.
// vmcnt(8) once per K-tile (P4) retires exactly tile kt+1's 8 loads.
// ---------------------------------------------------------------------------
template <typename OUT_T>
__global__ __launch_bounds__(512, 1) void gemm_bt256_kernel(const __bf16* __restrict__ A, int lda,
                                                            const __bf16* __restrict__ BT, int ldb,
                                                            OUT_T* __restrict__ C, int ldc, int K) {
    __shared__ __bf16 As[2][256 * 64];  // 32 KiB per buffer
    __shared__ __bf16 Bs[2][256 * 64];  // total 128 KiB
    const int n0 = blockIdx.x * 256;
    const int m0 = blockIdx.y * 256;
    const int tid = threadIdx.x;
    const int lane = tid & 63, quad = lane >> 4, l16 = lane & 15;
    const int wave = tid >> 6;
    const int wg64 = (wave >> 2) * 64;   // A row group offset
    const int wn32 = (wave & 3) * 32;    // B row group offset

    f32x4 acc[8][4] = {};

    // one staging round = 512 threads x 16B = 8 KiB = 64 LDS rows.
    // source column pre-swizzled so the swizzled ds_read sees logical order.
    auto STAGE_A = [&](int b, int kb, int round) {
        int c = round * 512 + tid;
        int row = c >> 3;
        int col8 = (c & 7) ^ (row & 7);
        GLD16(&A[(size_t)(m0 + row) * lda + kb + col8 * 8], &As[b][c * 8]);
    };
    auto STAGE_B = [&](int b, int kb, int round) {
        int c = round * 512 + tid;
        int row = c >> 3;
        int col8 = (c & 7) ^ (row & 7);
        GLD16(&BT[(size_t)(n0 + row) * ldb + kb + col8 * 8], &Bs[b][c * 8]);
    };

    const int nk = K >> 6;
    // prologue: stage tiles 0 and 1 in full (8 loads each)
#pragma unroll
    for (int r = 0; r < 4; r++) { STAGE_A(0, 0, r); STAGE_B(0, 0, r); }
#pragma unroll
    for (int r = 0; r < 4; r++) { STAGE_A(1, 64, r); STAGE_B(1, 64, r); }
    asm volatile("s_waitcnt vmcnt(8)" ::: "memory");  // tile 0 landed; tile 1 in flight
    __builtin_amdgcn_s_barrier();

    for (int kt = 0; kt < nk; ++kt) {
        const int cur = kt & 1;
        const __bf16* Asb = As[cur];
        const __bf16* Bsb = Bs[cur];
        const int kb2 = (kt + 2) << 6;
        const bool pf = (kt + 2) < nk;

        bf16x8 af[2][4], blo[2][2], bhi[2][2];

        // ---- P1: read A-lo(8) + B-lo(4); MFMA (i 0-3) x (j 0-1) ----
#pragma unroll
        for (int kk = 0; kk < 2; kk++) {
            int slot = ((kk * 4 + quad) ^ (l16 & 7)) * 8;
#pragma unroll
            for (int i = 0; i < 4; i++)
                af[kk][i] = *reinterpret_cast<const bf16x8*>(
                    &Asb[(wg64 + i * 16 + l16) * 64 + slot]);
#pragma unroll
            for (int j = 0; j < 2; j++)
                blo[kk][j] = *reinterpret_cast<const bf16x8*>(
                    &Bsb[(wn32 + j * 16 + l16) * 64 + slot]);
        }
        __builtin_amdgcn_s_barrier();
        asm volatile("s_waitcnt lgkmcnt(0)" ::: "memory");
        __builtin_amdgcn_s_setprio(1);
#pragma unroll
        for (int kk = 0; kk < 2; kk++)
#pragma unroll
            for (int i = 0; i < 4; i++)
#pragma unroll
                for (int j = 0; j < 2; j++)
                    acc[i][j] = MFMA_BF16(af[kk][i], blo[kk][j], acc[i][j]);
        __builtin_amdgcn_s_setprio(0);
        __builtin_amdgcn_s_barrier();

        // ---- P2: read B-hi(4); stage A rows 0-127 (freed in P1); A-lo reused ----
#pragma unroll
        for (int kk = 0; kk < 2; kk++) {
            int slot = ((kk * 4 + quad) ^ (l16 & 7)) * 8;
#pragma unroll
            for (int j = 0; j < 2; j++)
                bhi[kk][j] = *reinterpret_cast<const bf16x8*>(
                    &Bsb[(wn32 + 128 + j * 16 + l16) * 64 + slot]);
        }
        if (pf) { STAGE_A(cur, kb2, 0); STAGE_A(cur, kb2, 1); }
        __builtin_amdgcn_s_barrier();
        asm volatile("s_waitcnt lgkmcnt(0)" ::: "memory");
        __builtin_amdgcn_s_setprio(1);
#pragma unroll
        for (int kk = 0; kk < 2; kk++)
#pragma unroll
            for (int i = 0; i < 4; i++)
#pragma unroll
                for (int j = 0; j < 2; j++)
                    acc[i][j + 2] = MFMA_BF16(af[kk][i], bhi[kk][j], acc[i][j + 2]);
        __builtin_amdgcn_s_setprio(0);
        __builtin_amdgcn_s_barrier();

        // ---- P3: read A-hi(8); stage B rows 0-127 (freed in P1); B-hi reused ----
#pragma unroll
        for (int kk = 0; kk < 2; kk++) {
            int slot = ((kk * 4 + quad) ^ (l16 & 7)) * 8;
#pragma unroll
            for (int i = 0; i < 4; i++)
                af[kk][i] = *reinterpret_cast<const bf16x8*>(
                    &Asb[(wg64 + 128 + i * 16 + l16) * 64 + slot]);
        }
        if (pf) { STAGE_B(cur, kb2, 0); STAGE_B(cur, kb2, 1); }
        __builtin_amdgcn_s_barrier();
        asm volatile("s_waitcnt lgkmcnt(0)" ::: "memory");
        __builtin_amdgcn_s_setprio(1);
#pragma unroll
        for (int kk = 0; kk < 2; kk++)
#pragma unroll
            for (int i = 0; i < 4; i++)
#pragma unroll
                for (int j = 0; j < 2; j++)
                    acc[i + 4][j + 2] = MFMA_BF16(af[kk][i], bhi[kk][j], acc[i + 4][j + 2]);
        __builtin_amdgcn_s_setprio(0);
        __builtin_amdgcn_s_barrier();

        // ---- P4: no reads; stage A+B rows 128-255 (freed in P3/P2); vmcnt ----
        if (pf) { STAGE_A(cur, kb2, 2); STAGE_A(cur, kb2, 3);
                  STAGE_B(cur, kb2, 2); STAGE_B(cur, kb2, 3); }
        __builtin_amdgcn_s_barrier();
        __builtin_amdgcn_s_setprio(1);
#pragma unroll
        for (int kk = 0; kk < 2; kk++)
#pragma unroll
            for (int i = 0; i < 4; i++)
#pragma unroll
                for (int j = 0; j < 2; j++)
                    acc[i + 4][j] = MFMA_BF16(af[kk][i], blo[kk][j], acc[i + 4][j]);
        __builtin_amdgcn_s_setprio(0);
        if (pf) {
            asm volatile("s_waitcnt vmcnt(8)" ::: "memory");  // tile kt+1 fully landed
        } else {
            asm volatile("s_waitcnt vmcnt(0)" ::: "memory");  // pipeline tail
        }
        __builtin_amdgcn_s_barrier();
    }

#pragma unroll
    for (int i = 0; i < 8; i++)
#pragma unroll
        for (int j = 0; j < 4; j++)
#pragma unroll
            for (int r = 0; r < 4; r++) {
                int row = m0 + wg64 + (i & 3) * 16 + (i >> 2) * 128 + quad * 4 + r;
                int col = n0 + wn32 + (j & 1) * 16 + (j >> 1) * 128 + l16;
                C[(size_t)row * ldc + col] = (OUT_T)acc[i][j][r];
            }
}

// ---------------------------------------------------------------------------
// Flash attention v7 (causal, GQA) — shift-free softmax + MFMA row-sums,
// 2 q-heads per block (K/V staged once serve both), split-KV CS=16.
// ---------------------------------------------------------------------------
__global__ __launch_bounds__(256) void attn_kernel(const __bf16* __restrict__ QKV,
                                                   const __bf16* __restrict__ VT,
                                                   __bf16* __restrict__ Ao,
                                                   __bf16* __restrict__ Opart,
                                                   float* __restrict__ Lp) {
    __shared__ __bf16 Ks[64 * 128];      // K tile [64 kv][128 d], chunk-swizzled
    __shared__ __bf16 Vs[128 * 64];      // V^T tile [128 d][64 kv], chunk-swizzled
    __shared__ __bf16 Pl[4][2][16 * 72]; // per-wave, per-head P buffer (+8 pad)
    int x = blockIdx.x;                  // chunk-slot, heavy-first mapping
    int qt, c;
    if (x < 32) { qt = 31 - (x >> 1); c = x & 1; }   // qt 16..31, 2 chunks
    else        { qt = 47 - x;        c = 0;     }   // qt 15..0, 1 chunk
    int hp = blockIdx.y;                 // head pair 0..15
    int kvh = hp >> 1;
    int h0 = kvh * 4 + (hp & 1) * 2;     // absolute heads h0, h0+1
    int t0 = c ? 16 : 0;
    int t1 = c ? qt : min(qt, 15);
    int tid = threadIdx.x;
    int wave = tid >> 6, lane = tid & 63, quad = lane >> 4, l16 = lane & 15;
    int wq = qt * 64 + wave * 16;        // this wave's 16 q-rows
    const __bf16* Kb = QKV + HID + (size_t)kvh * HD;
    const __bf16* Vt = VT + (size_t)kvh * HD * S_LEN;

    // Q fragments for both heads (pre-scaled by scale*log2e via Wq)
    bf16x8 qf[2][4];
#pragma unroll
    for (int h = 0; h < 2; h++)
#pragma unroll
        for (int ks = 0; ks < 4; ks++)
            qf[h][ks] = *reinterpret_cast<const bf16x8*>(
                &QKV[(size_t)(wq + l16) * LDQKV + (h0 + h) * HD + ks * 32 + quad * 8]);

    bf16x8 ones;
#pragma unroll
    for (int j = 0; j < 8; j++) ones[j] = (__bf16)1.0f;

    f32x4 acc_o[2][8] = {};
    f32x4 lacc[2] = {};

    for (int t = t0; t <= t1; t++) {
        int kv0 = t << 6;
        bool diag = (t == qt);
        __syncthreads();  // previous tile's LDS reads done
        // ---- stage K tile: 1024 chunks of 16B, source-side XOR swizzle
#pragma unroll
        for (int i = 0; i < 4; i++) {
            int cc = i * 256 + tid;
            int row = cc >> 4, sub = cc & 15;
            int col8 = sub ^ (row & 15);
            GLD16(&Kb[(size_t)(kv0 + row) * LDQKV + col8 * 8], &Ks[cc * 8]);
        }
        // ---- stage V^T tile: 1024 chunks of 16B
#pragma unroll
        for (int i = 0; i < 4; i++) {
            int cc = i * 256 + tid;
            int row = cc >> 3, sub = cc & 7;
            int col8 = sub ^ (row & 7);
            GLD16(&Vt[(size_t)row * S_LEN + kv0 + col8 * 8], &Vs[cc * 8]);
        }
        __syncthreads();  // drains vmcnt + barrier

        // ---- S = Q K^T for both heads (kf shared)
        f32x4 sacc[2][4] = {};
#pragma unroll
        for (int ks = 0; ks < 4; ks++) {
            bf16x8 kf[4];
#pragma unroll
            for (int n = 0; n < 4; n++) {
                int row = n * 16 + l16;
                int sub = (ks * 4 + quad) ^ l16;
                kf[n] = *reinterpret_cast<const bf16x8*>(&Ks[row * 128 + sub * 8]);
            }
#pragma unroll
            for (int n = 0; n < 4; n++) {
                sacc[0][n] = MFMA_BF16(qf[0][ks], kf[n], sacc[0][n]);
                sacc[1][n] = MFMA_BF16(qf[1][ks], kf[n], sacc[1][n]);
            }
        }
        // ---- shift-free softmax: P = exp2(S); no reductions at all
#pragma unroll
        for (int h = 0; h < 2; h++) {
            __bf16* Pw = Pl[wave][h];
#pragma unroll
            for (int r = 0; r < 4; r++) {
                int row = wq + quad * 4 + r;
#pragma unroll
                for (int n = 0; n < 4; n++) {
                    float v = sacc[h][n][r];
                    if (diag) {
                        int col = kv0 + n * 16 + l16;
                        if (col > row) v = -1e30f;  // causal mask (diag tile only)
                    }
                    Pw[(quad * 4 + r) * 72 + n * 16 + l16] =
                        (__bf16)__builtin_amdgcn_exp2f(v);
                }
            }
        }
        // ---- O += P V ; l += P * ones (row-sums via MFMA, lands in all lanes)
#pragma unroll
        for (int ks = 0; ks < 2; ks++) {
            bf16x8 pf0 = *reinterpret_cast<const bf16x8*>(
                &Pl[wave][0][l16 * 72 + ks * 32 + quad * 8]);
            bf16x8 pf1 = *reinterpret_cast<const bf16x8*>(
                &Pl[wave][1][l16 * 72 + ks * 32 + quad * 8]);
            lacc[0] = MFMA_BF16(pf0, ones, lacc[0]);
            lacc[1] = MFMA_BF16(pf1, ones, lacc[1]);
#pragma unroll
            for (int dn = 0; dn < 8; dn++) {
                int row = dn * 16 + l16;
                int sub = (ks * 4 + quad) ^ (row & 7);
                bf16x8 vf = *reinterpret_cast<const bf16x8*>(&Vs[row * 64 + sub * 8]);
                acc_o[0][dn] = MFMA_BF16(pf0, vf, acc_o[0][dn]);
                acc_o[1][dn] = MFMA_BF16(pf1, vf, acc_o[1][dn]);
            }
        }
    }

    // ---- epilogue
    if (qt < 16) {
        // single chunk: normalized output
#pragma unroll
        for (int h = 0; h < 2; h++) {
            float rl[4];
#pragma unroll
            for (int r = 0; r < 4; r++) rl[r] = 1.0f / lacc[h][r];
#pragma unroll
            for (int dn = 0; dn < 8; dn++)
#pragma unroll
                for (int r = 0; r < 4; r++) {
                    int row = wq + quad * 4 + r;
                    int col = (h0 + h) * HD + dn * 16 + l16;
                    Ao[(size_t)row * HID + col] = (__bf16)(acc_o[h][dn][r] * rl[r]);
                }
        }
    } else {
        // two-chunk qt: write unnormalized O + l partials
        int s = (qt - 16) * 2 + c;
#pragma unroll
        for (int h = 0; h < 2; h++) {
            size_t base = ((size_t)(h0 + h) * 32 + s) * 64 + wave * 16;
#pragma unroll
            for (int dn = 0; dn < 8; dn++)
#pragma unroll
                for (int r = 0; r < 4; r++)
                    Opart[(base + quad * 4 + r) * 128 + dn * 16 + l16] =
                        (__bf16)acc_o[h][dn][r];
            if (l16 == 0) {
#pragma unroll
                for (int r = 0; r < 4; r++)
                    Lp[base + quad * 4 + r] = lacc[h][r];
            }
        }
    }
}

// ---------------------------------------------------------------------------
// combine two chunks (qt >= 16): O = (O0 + O1) / (l0 + l1). Shift-free, no exp.
// ---------------------------------------------------------------------------
__global__ __launch_bounds__(256) void attn_combine(const __bf16* __restrict__ Opart,
                                                    const float* __restrict__ Lp,
                                                    __bf16* __restrict__ Ao) {
    int qt = 16 + (int)blockIdx.x;  // 16..31
    int h = blockIdx.y;
    int tid = threadIdx.x;
    size_t b0 = ((size_t)h * 32 + (qt - 16) * 2) * 64;
    size_t b1 = b0 + 64;
#pragma unroll 4
    for (int i = 0; i < 32; i++) {
        int el = i * 256 + tid;
        int rl = el >> 7, col = el & 127;
        float l = Lp[b0 + rl] + Lp[b1 + rl];
        float O = (float)Opart[(b0 + rl) * 128 + col] + (float)Opart[(b1 + rl) * 128 + col];
        int row = qt * 64 + rl;
        Ao[(size_t)row * HID + h * HD + col] = (__bf16)(O / l);
    }
}

// ---------------------------------------------------------------------------
extern "C" void kernel_launch(void* const* d_in, const int* in_sizes, int n_in,
                              void* d_out, int out_size, void* d_ws, size_t ws_size,
                              hipStream_t stream) {
    const float* hs = (const float*)d_in[0];
    // d_in[1] = attention_mask (pure causal; applied analytically)
    const float* wq = (const float*)d_in[2];
    const float* wk = (const float*)d_in[3];
    const float* wv = (const float*)d_in[4];
    const float* wo = (const float*)d_in[5];
    float* out = (float*)d_out;

    char* ws = (char*)d_ws;
    // workspace (92 MB with reuse)
    __bf16* WqkvT = (__bf16*)(ws + (size_t)0);          // 48 MB [6144][4096]; reused for WoT
    __bf16* Opart = (__bf16*)(ws + (size_t)0);          // 17 MB attn partials (weight window,
    float*  Lp    = (float*)(ws + ((size_t)20 << 20));  // 0.3 MB  dead during attention)
    __bf16* Xb    = (__bf16*)(ws + ((size_t)48 << 20)); // 16 MB [2048][4096]; reused for attn out
    __bf16* QKV   = (__bf16*)(ws + ((size_t)64 << 20)); // 24 MB [2048][6144]
    __bf16* VTg   = (__bf16*)(ws + ((size_t)88 << 20)); //  4 MB [1024][2048]
    __bf16* Ab    = Xb;

    const int nX = S_LEN * HID;  // 8M
    const float SC2 = 0.12751743f;  // (1/sqrt(128)) * log2(e), folded into Wq

    // 1) cast hidden to bf16
    cast_bf16_kernel<<<nX / 4 / 256, 256, 0, stream>>>(hs, Xb, nX);
    // 2) fused W_{q,k,v}^T (Wq pre-scaled into exp2 domain)
    transpose_cast_kernel<<<dim3(128, 128), dim3(32, 8), 0, stream>>>(wq, WqkvT, HID, HID, SC2);
    transpose_cast_kernel<<<dim3(32, 128), dim3(32, 8), 0, stream>>>(
        wk, WqkvT + (size_t)4096 * HID, HID, NKV * HD, 1.0f);
    transpose_cast_kernel<<<dim3(32, 128), dim3(32, 8), 0, stream>>>(
        wv, WqkvT + (size_t)5120 * HID, HID, NKV * HD, 1.0f);
    // 3) one fused QKV GEMM: [2048][6144] via fixed 256x256 8-phase kernel
    gemm_bt256_kernel<__bf16><<<dim3(LDQKV / 256, S_LEN / 256), 512, 0, stream>>>(
        Xb, HID, WqkvT, HID, QKV, LDQKV, HID);
    // 4) V^T for PV B-operand (V = QKV cols 5120..6143)
    transpose_bf16_kernel<<<dim3(32, 64), dim3(32, 8), 0, stream>>>(
        QKV + 5120, LDQKV, VTg, S_LEN);
    // 5) flash attention (2-head blocks, shift-free softmax, split-KV) + combine
    attn_kernel<<<dim3(48, 16), 256, 0, stream>>>(QKV, VTg, Ab, Opart, Lp);
    attn_combine<<<dim3(16, 32), 256, 0, stream>>>(Opart, Lp, Ab);
    // 6) out = Ab @ WoT^T (fp32), 128x128 kernel: 512 blocks = full CU coverage
    transpose_cast_kernel<<<dim3(128, 128), dim3(32, 8), 0, stream>>>(wo, WqkvT, HID, HID, 1.0f);
    gemm_bt_kernel<float><<<dim3(HID / 128, S_LEN / 128), 256, 0, stream>>>(
        Ab, HID, WqkvT, HID, out, HID, HID);
}

// Round 3
// 516.757 us; speedup vs baseline: 1.2211x; 1.0400x over previous
//
#include <hip/hip_runtime.h>
#include <hip/hip_bf16.h>

// Problem constants
#define S_LEN 2048
#define HID 4096
#define NH 32
#define NKV 8
#define HD 128
#define LDQKV 6144   // fused QKV output: cols [0,4096)=Q, [4096,5120)=K, [5120,6144)=V

typedef __bf16 bf16x8 __attribute__((ext_vector_type(8)));
typedef __bf16 bf16x4 __attribute__((ext_vector_type(4)));
typedef float f32x4 __attribute__((ext_vector_type(4)));

// async global->LDS, 16B per lane (HW: wave-uniform LDS base + lane*16)
#define GLD16(gp, lp)                                                                   \
    __builtin_amdgcn_global_load_lds((const __attribute__((address_space(1))) void*)(gp), \
                                     (__attribute__((address_space(3))) void*)(lp), 16, 0, 0)

#define MFMA_BF16(a, b, c) __builtin_amdgcn_mfma_f32_16x16x32_bf16((a), (b), (c), 0, 0, 0)

// ---------------------------------------------------------------------------
__global__ void cast_bf16_kernel(const float* __restrict__ x, __bf16* __restrict__ y, int n) {
    int i = (blockIdx.x * blockDim.x + threadIdx.x) * 4;
    if (i < n) {
        float4 v = *reinterpret_cast<const float4*>(x + i);
        bf16x4 o;
        o.x = (__bf16)v.x; o.y = (__bf16)v.y; o.z = (__bf16)v.z; o.w = (__bf16)v.w;
        *reinterpret_cast<bf16x4*>(y + i) = o;
    }
}

// ---------------------------------------------------------------------------
// transpose + cast + scale: W [K][N] fp32 -> WT [N][K] bf16 * scale
// ---------------------------------------------------------------------------
__global__ void transpose_cast_kernel(const float* __restrict__ W, __bf16* __restrict__ WT,
                                      int K, int N, float scale) {
    __shared__ float tile[32][33];
    int bx = blockIdx.x;  // over N/32
    int by = blockIdx.y;  // over K/32
    int tx = threadIdx.x; // 32
    int ty = threadIdx.y; // 8
    int n = bx * 32 + tx;
#pragma unroll
    for (int i = 0; i < 4; i++) {
        int k = by * 32 + ty + i * 8;
        tile[ty + i * 8][tx] = W[(size_t)k * N + n];
    }
    __syncthreads();
    int k2 = by * 32 + tx;
#pragma unroll
    for (int i = 0; i < 4; i++) {
        int n2 = bx * 32 + ty + i * 8;
        WT[(size_t)n2 * K + k2] = (__bf16)(tile[tx][ty + i * 8] * scale);
    }
}

// ---------------------------------------------------------------------------
// strided bf16 transpose: V [R][C] (ld=ldin) -> VT [C][R] (ld=ldout)
// ---------------------------------------------------------------------------
__global__ void transpose_bf16_kernel(const __bf16* __restrict__ V, int ldin,
                                      __bf16* __restrict__ VT, int ldout) {
    __shared__ __bf16 tile[32][33];
    int bx = blockIdx.x;
    int by = blockIdx.y;
    int tx = threadIdx.x;
    int ty = threadIdx.y;
#pragma unroll
    for (int i = 0; i < 4; i++)
        tile[ty + i * 8][tx] = V[(size_t)(by * 32 + ty + i * 8) * ldin + bx * 32 + tx];
    __syncthreads();
#pragma unroll
    for (int i = 0; i < 4; i++)
        VT[(size_t)(bx * 32 + ty + i * 8) * ldout + by * 32 + tx] = tile[tx][ty + i * 8];
}

// ---------------------------------------------------------------------------
// Pipelined NT GEMM: C = A[M,K] * BT[N,K]^T, bf16 in, fp32 acc.
// Tile BM x 256, BK=64; 512 threads = 8 waves (2 A-groups x 4 B-groups);
// per-wave output (BM/2) x 64. Two kk-phases per K-tile, 32*MR MFMA each.
// One-phase-ahead ds_read pipeline: phase issues the NEXT set's reads, then
// lgkmcnt(NREADS) waits only the PREVIOUS set -> LDS port drains under the
// matrix-pipe backlog instead of serializing with it.
// Hazard fences (all provable):
//  - reads of tile kt+1 gated by vmcnt(0)+barrier (only outstanding VMEM =
//    tile kt+1's own GLDs, issued one full K-tile earlier -> no drain cost);
//  - stage of tile kt+2 into buf cur gated by barrier preceded by each
//    wave's lgkmcnt proving ALL its tile-kt reads completed.
// ---------------------------------------------------------------------------
template <int BM, typename OUT_T>
__global__ __launch_bounds__(512, 1) void gemm_pipe_kernel(const __bf16* __restrict__ A, int lda,
                                                           const __bf16* __restrict__ BT, int ldb,
                                                           OUT_T* __restrict__ C, int ldc, int K) {
    constexpr int MR = BM / 128;       // A frags per kk per wave = 4*MR
    constexpr int AROUNDS = BM / 64;   // GLD16 rounds for the A tile (2 or 4)
    constexpr int NREADS = 4 * MR + 4; // ds_reads per kk-set (8 or 12)
    __shared__ __bf16 As[2][BM * 64];
    __shared__ __bf16 Bs[2][256 * 64];
    const int n0 = blockIdx.x * 256;
    const int m0 = blockIdx.y * BM;
    const int tid = threadIdx.x;
    const int lane = tid & 63, quad = lane >> 4, l16 = lane & 15;
    const int wave = tid >> 6;
    const int wg = (wave >> 2) * 64;   // A row-group offset (0/64); +128 for hi when MR==2
    const int wn32 = (wave & 3) * 32;  // B row-group offset; +128 for hi

    f32x4 acc[4 * MR][4] = {};

    // stage tile kb into buffer b: source column pre-swizzled (slot ^ row&7)
    auto STAGE = [&](int b, int kb) {
#pragma unroll
        for (int r = 0; r < AROUNDS; r++) {
            int c = r * 512 + tid;
            int row = c >> 3;
            int col8 = (c & 7) ^ (row & 7);
            GLD16(&A[(size_t)(m0 + row) * lda + kb + col8 * 8], &As[b][c * 8]);
        }
#pragma unroll
        for (int r = 0; r < 4; r++) {
            int c = r * 512 + tid;
            int row = c >> 3;
            int col8 = (c & 7) ^ (row & 7);
            GLD16(&BT[(size_t)(n0 + row) * ldb + kb + col8 * 8], &Bs[b][c * 8]);
        }
    };

    // issue the ds_reads for one kk-set (NREADS ds_read_b128, swizzled slots)
    auto READ_SET = [&](const __bf16* Asb, const __bf16* Bsb, int kk,
                        bf16x8 (&fa)[4 * MR], bf16x8 (&fb)[4]) {
        int slot = ((kk * 4 + quad) ^ (l16 & 7)) * 8;
#pragma unroll
        for (int i = 0; i < 4 * MR; i++) {
            int row = wg + (i & 3) * 16 + (i >> 2) * 128 + l16;
            fa[i] = *reinterpret_cast<const bf16x8*>(&Asb[row * 64 + slot]);
        }
#pragma unroll
        for (int j = 0; j < 4; j++) {
            int row = wn32 + (j & 1) * 16 + (j >> 1) * 128 + l16;
            fb[j] = *reinterpret_cast<const bf16x8*>(&Bsb[row * 64 + slot]);
        }
    };

    auto MF = [&](bf16x8 (&fa)[4 * MR], bf16x8 (&fb)[4]) {
        __builtin_amdgcn_s_setprio(1);
#pragma unroll
        for (int i = 0; i < 4 * MR; i++)
#pragma unroll
            for (int j = 0; j < 4; j++)
                acc[i][j] = MFMA_BF16(fa[i], fb[j], acc[i][j]);
        __builtin_amdgcn_s_setprio(0);
    };

    // wait until only the newest kk-set's reads are outstanding (prev set done)
    auto WAIT_SET = [&]() {
        if constexpr (NREADS == 12) {
            asm volatile("s_waitcnt lgkmcnt(12)" ::: "memory");
        } else {
            asm volatile("s_waitcnt lgkmcnt(8)" ::: "memory");
        }
        __builtin_amdgcn_sched_barrier(0);
    };

    const int nk = K >> 6;
    bf16x8 fa0[4 * MR], fb0[4], fa1[4 * MR], fb1[4];

    // prologue: stage tiles 0 and 1; wait own tile-0 GLDs; barrier -> all landed
    STAGE(0, 0);
    STAGE(1, 64);
    if constexpr (AROUNDS == 4) {
        asm volatile("s_waitcnt vmcnt(8)" ::: "memory");
    } else {
        asm volatile("s_waitcnt vmcnt(6)" ::: "memory");
    }
    __builtin_amdgcn_sched_barrier(0);
    __builtin_amdgcn_s_barrier();
    READ_SET(As[0], Bs[0], 0, fa0, fb0);  // kk0 of tile 0 -> set0

    for (int kt = 0; kt < nk; ++kt) {
        const int cur = kt & 1;
        // ---- phase A: compute kk0 (set0), prefetch kk1 (set1) ----
        READ_SET(As[cur], Bs[cur], 1, fa1, fb1);
        WAIT_SET();  // set0 complete (older than the 12 just issued)
        MF(fa0, fb0);
        // ---- phase B: compute kk1 (set1), prefetch next tile's kk0 (set0) ----
        if (kt + 1 < nk) {
            asm volatile("s_waitcnt vmcnt(0)" ::: "memory");  // own tile kt+1 GLDs landed
            __builtin_amdgcn_sched_barrier(0);
            __builtin_amdgcn_s_barrier();                     // all waves' tile kt+1 landed
            READ_SET(As[cur ^ 1], Bs[cur ^ 1], 0, fa0, fb0);
            WAIT_SET();  // set1 complete
        } else {
            asm volatile("s_waitcnt lgkmcnt(0)" ::: "memory");
            __builtin_amdgcn_sched_barrier(0);
        }
        if (kt + 2 < nk) {
            __builtin_amdgcn_s_barrier();  // all waves done reading tile kt -> overwrite ok
            STAGE(cur, (kt + 2) << 6);
        }
        MF(fa1, fb1);
    }

#pragma unroll
    for (int i = 0; i < 4 * MR; i++)
#pragma unroll
        for (int j = 0; j < 4; j++)
#pragma unroll
            for (int r = 0; r < 4; r++) {
                int row = m0 + wg + (i & 3) * 16 + (i >> 2) * 128 + quad * 4 + r;
                int col = n0 + wn32 + (j & 1) * 16 + (j >> 1) * 128 + l16;
                C[(size_t)row * ldc + col] = (OUT_T)acc[i][j][r];
            }
}

// ---------------------------------------------------------------------------
// Flash attention v7 (causal, GQA) — shift-free softmax + MFMA row-sums,
// 2 q-heads per block (K/V staged once serve both), split-KV CS=16.
// ---------------------------------------------------------------------------
__global__ __launch_bounds__(256) void attn_kernel(const __bf16* __restrict__ QKV,
                                                   const __bf16* __restrict__ VT,
                                                   __bf16* __restrict__ Ao,
                                                   __bf16* __restrict__ Opart,
                                                   float* __restrict__ Lp) {
    __shared__ __bf16 Ks[64 * 128];      // K tile [64 kv][128 d], chunk-swizzled
    __shared__ __bf16 Vs[128 * 64];      // V^T tile [128 d][64 kv], chunk-swizzled
    __shared__ __bf16 Pl[4][2][16 * 72]; // per-wave, per-head P buffer (+8 pad)
    int x = blockIdx.x;                  // chunk-slot, heavy-first mapping
    int qt, c;
    if (x < 32) { qt = 31 - (x >> 1); c = x & 1; }   // qt 16..31, 2 chunks
    else        { qt = 47 - x;        c = 0;     }   // qt 15..0, 1 chunk
    int hp = blockIdx.y;                 // head pair 0..15
    int kvh = hp >> 1;
    int h0 = kvh * 4 + (hp & 1) * 2;     // absolute heads h0, h0+1
    int t0 = c ? 16 : 0;
    int t1 = c ? qt : min(qt, 15);
    int tid = threadIdx.x;
    int wave = tid >> 6, lane = tid & 63, quad = lane >> 4, l16 = lane & 15;
    int wq = qt * 64 + wave * 16;        // this wave's 16 q-rows
    const __bf16* Kb = QKV + HID + (size_t)kvh * HD;
    const __bf16* Vt = VT + (size_t)kvh * HD * S_LEN;

    // Q fragments for both heads (pre-scaled by scale*log2e via Wq)
    bf16x8 qf[2][4];
#pragma unroll
    for (int h = 0; h < 2; h++)
#pragma unroll
        for (int ks = 0; ks < 4; ks++)
            qf[h][ks] = *reinterpret_cast<const bf16x8*>(
                &QKV[(size_t)(wq + l16) * LDQKV + (h0 + h) * HD + ks * 32 + quad * 8]);

    bf16x8 ones;
#pragma unroll
    for (int j = 0; j < 8; j++) ones[j] = (__bf16)1.0f;

    f32x4 acc_o[2][8] = {};
    f32x4 lacc[2] = {};

    for (int t = t0; t <= t1; t++) {
        int kv0 = t << 6;
        bool diag = (t == qt);
        __syncthreads();  // previous tile's LDS reads done
        // ---- stage K tile: 1024 chunks of 16B, source-side XOR swizzle
#pragma unroll
        for (int i = 0; i < 4; i++) {
            int cc = i * 256 + tid;
            int row = cc >> 4, sub = cc & 15;
            int col8 = sub ^ (row & 15);
            GLD16(&Kb[(size_t)(kv0 + row) * LDQKV + col8 * 8], &Ks[cc * 8]);
        }
        // ---- stage V^T tile: 1024 chunks of 16B
#pragma unroll
        for (int i = 0; i < 4; i++) {
            int cc = i * 256 + tid;
            int row = cc >> 3, sub = cc & 7;
            int col8 = sub ^ (row & 7);
            GLD16(&Vt[(size_t)row * S_LEN + kv0 + col8 * 8], &Vs[cc * 8]);
        }
        __syncthreads();  // drains vmcnt + barrier

        // ---- S = Q K^T for both heads (kf shared)
        f32x4 sacc[2][4] = {};
#pragma unroll
        for (int ks = 0; ks < 4; ks++) {
            bf16x8 kf[4];
#pragma unroll
            for (int n = 0; n < 4; n++) {
                int row = n * 16 + l16;
                int sub = (ks * 4 + quad) ^ l16;
                kf[n] = *reinterpret_cast<const bf16x8*>(&Ks[row * 128 + sub * 8]);
            }
#pragma unroll
            for (int n = 0; n < 4; n++) {
                sacc[0][n] = MFMA_BF16(qf[0][ks], kf[n], sacc[0][n]);
                sacc[1][n] = MFMA_BF16(qf[1][ks], kf[n], sacc[1][n]);
            }
        }
        // ---- shift-free softmax: P = exp2(S); no reductions at all
#pragma unroll
        for (int h = 0; h < 2; h++) {
            __bf16* Pw = Pl[wave][h];
#pragma unroll
            for (int r = 0; r < 4; r++) {
                int row = wq + quad * 4 + r;
#pragma unroll
                for (int n = 0; n < 4; n++) {
                    float v = sacc[h][n][r];
                    if (diag) {
                        int col = kv0 + n * 16 + l16;
                        if (col > row) v = -1e30f;  // causal mask (diag tile only)
                    }
                    Pw[(quad * 4 + r) * 72 + n * 16 + l16] =
                        (__bf16)__builtin_amdgcn_exp2f(v);
                }
            }
        }
        // ---- O += P V ; l += P * ones (row-sums via MFMA, lands in all lanes)
#pragma unroll
        for (int ks = 0; ks < 2; ks++) {
            bf16x8 pf0 = *reinterpret_cast<const bf16x8*>(
                &Pl[wave][0][l16 * 72 + ks * 32 + quad * 8]);
            bf16x8 pf1 = *reinterpret_cast<const bf16x8*>(
                &Pl[wave][1][l16 * 72 + ks * 32 + quad * 8]);
            lacc[0] = MFMA_BF16(pf0, ones, lacc[0]);
            lacc[1] = MFMA_BF16(pf1, ones, lacc[1]);
#pragma unroll
            for (int dn = 0; dn < 8; dn++) {
                int row = dn * 16 + l16;
                int sub = (ks * 4 + quad) ^ (row & 7);
                bf16x8 vf = *reinterpret_cast<const bf16x8*>(&Vs[row * 64 + sub * 8]);
                acc_o[0][dn] = MFMA_BF16(pf0, vf, acc_o[0][dn]);
                acc_o[1][dn] = MFMA_BF16(pf1, vf, acc_o[1][dn]);
            }
        }
    }

    // ---- epilogue
    if (qt < 16) {
        // single chunk: normalized output
#pragma unroll
        for (int h = 0; h < 2; h++) {
            float rl[4];
#pragma unroll
            for (int r = 0; r < 4; r++) rl[r] = 1.0f / lacc[h][r];
#pragma unroll
            for (int dn = 0; dn < 8; dn++)
#pragma unroll
                for (int r = 0; r < 4; r++) {
                    int row = wq + quad * 4 + r;
                    int col = (h0 + h) * HD + dn * 16 + l16;
                    Ao[(size_t)row * HID + col] = (__bf16)(acc_o[h][dn][r] * rl[r]);
                }
        }
    } else {
        // two-chunk qt: write unnormalized O + l partials
        int s = (qt - 16) * 2 + c;
#pragma unroll
        for (int h = 0; h < 2; h++) {
            size_t base = ((size_t)(h0 + h) * 32 + s) * 64 + wave * 16;
#pragma unroll
            for (int dn = 0; dn < 8; dn++)
#pragma unroll
                for (int r = 0; r < 4; r++)
                    Opart[(base + quad * 4 + r) * 128 + dn * 16 + l16] =
                        (__bf16)acc_o[h][dn][r];
            if (l16 == 0) {
#pragma unroll
                for (int r = 0; r < 4; r++)
                    Lp[base + quad * 4 + r] = lacc[h][r];
            }
        }
    }
}

// ---------------------------------------------------------------------------
// combine two chunks (qt >= 16): O = (O0 + O1) / (l0 + l1). Shift-free, no exp.
// ---------------------------------------------------------------------------
__global__ __launch_bounds__(256) void attn_combine(const __bf16* __restrict__ Opart,
                                                    const float* __restrict__ Lp,
                                                    __bf16* __restrict__ Ao) {
    int qt = 16 + (int)blockIdx.x;  // 16..31
    int h = blockIdx.y;
    int tid = threadIdx.x;
    size_t b0 = ((size_t)h * 32 + (qt - 16) * 2) * 64;
    size_t b1 = b0 + 64;
#pragma unroll 4
    for (int i = 0; i < 32; i++) {
        int el = i * 256 + tid;
        int rl = el >> 7, col = el & 127;
        float l = Lp[b0 + rl] + Lp[b1 + rl];
        float O = (float)Opart[(b0 + rl) * 128 + col] + (float)Opart[(b1 + rl) * 128 + col];
        int row = qt * 64 + rl;
        Ao[(size_t)row * HID + h * HD + col] = (__bf16)(O / l);
    }
}

// ---------------------------------------------------------------------------
extern "C" void kernel_launch(void* const* d_in, const int* in_sizes, int n_in,
                              void* d_out, int out_size, void* d_ws, size_t ws_size,
                              hipStream_t stream) {
    const float* hs = (const float*)d_in[0];
    // d_in[1] = attention_mask (pure causal; applied analytically)
    const float* wq = (const float*)d_in[2];
    const float* wk = (const float*)d_in[3];
    const float* wv = (const float*)d_in[4];
    const float* wo = (const float*)d_in[5];
    float* out = (float*)d_out;

    char* ws = (char*)d_ws;
    // workspace (92 MB with reuse)
    __bf16* WqkvT = (__bf16*)(ws + (size_t)0);          // 48 MB [6144][4096]; reused for WoT
    __bf16* Opart = (__bf16*)(ws + (size_t)0);          // 17 MB attn partials (weight window,
    float*  Lp    = (float*)(ws + ((size_t)20 << 20));  // 0.3 MB  dead during attention)
    __bf16* Xb    = (__bf16*)(ws + ((size_t)48 << 20)); // 16 MB [2048][4096]; reused for attn out
    __bf16* QKV   = (__bf16*)(ws + ((size_t)64 << 20)); // 24 MB [2048][6144]
    __bf16* VTg   = (__bf16*)(ws + ((size_t)88 << 20)); //  4 MB [1024][2048]
    __bf16* Ab    = Xb;

    const int nX = S_LEN * HID;  // 8M
    const float SC2 = 0.12751743f;  // (1/sqrt(128)) * log2(e), folded into Wq

    // 1) cast hidden to bf16
    cast_bf16_kernel<<<nX / 4 / 256, 256, 0, stream>>>(hs, Xb, nX);
    // 2) fused W_{q,k,v}^T (Wq pre-scaled into exp2 domain)
    transpose_cast_kernel<<<dim3(128, 128), dim3(32, 8), 0, stream>>>(wq, WqkvT, HID, HID, SC2);
    transpose_cast_kernel<<<dim3(32, 128), dim3(32, 8), 0, stream>>>(
        wk, WqkvT + (size_t)4096 * HID, HID, NKV * HD, 1.0f);
    transpose_cast_kernel<<<dim3(32, 128), dim3(32, 8), 0, stream>>>(
        wv, WqkvT + (size_t)5120 * HID, HID, NKV * HD, 1.0f);
    // 3) one fused QKV GEMM: [2048][6144], 256x256 pipelined (grid 24x8)
    gemm_pipe_kernel<256, __bf16><<<dim3(LDQKV / 256, S_LEN / 256), 512, 0, stream>>>(
        Xb, HID, WqkvT, HID, QKV, LDQKV, HID);
    // 4) V^T for PV B-operand (V = QKV cols 5120..6143)
    transpose_bf16_kernel<<<dim3(32, 64), dim3(32, 8), 0, stream>>>(
        QKV + 5120, LDQKV, VTg, S_LEN);
    // 5) flash attention (2-head blocks, shift-free softmax, split-KV) + combine
    attn_kernel<<<dim3(48, 16), 256, 0, stream>>>(QKV, VTg, Ab, Opart, Lp);
    attn_combine<<<dim3(16, 32), 256, 0, stream>>>(Opart, Lp, Ab);
    // 6) out = Ab @ WoT^T (fp32), 128x256 pipelined: grid 16x16 = 256 blocks
    transpose_cast_kernel<<<dim3(128, 128), dim3(32, 8), 0, stream>>>(wo, WqkvT, HID, HID, 1.0f);
    gemm_pipe_kernel<128, float><<<dim3(HID / 256, S_LEN / 128), 512, 0, stream>>>(
        Ab, HID, WqkvT, HID, out, HID, HID);
}

// Round 4
// 481.044 us; speedup vs baseline: 1.3118x; 1.0742x over previous
//
#include <hip/hip_runtime.h>
#include <hip/hip_bf16.h>

// Problem constants
#define S_LEN 2048
#define HID 4096
#define NH 32
#define NKV 8
#define HD 128
#define LDQKV 6144   // fused QKV output: cols [0,4096)=Q, [4096,5120)=K, [5120,6144)=V

typedef __bf16 bf16x8 __attribute__((ext_vector_type(8)));
typedef __bf16 bf16x4 __attribute__((ext_vector_type(4)));
typedef float f32x4 __attribute__((ext_vector_type(4)));

// async global->LDS, 16B per lane (HW: wave-uniform LDS base + lane*16)
#define GLD16(gp, lp)                                                                   \
    __builtin_amdgcn_global_load_lds((const __attribute__((address_space(1))) void*)(gp), \
                                     (__attribute__((address_space(3))) void*)(lp), 16, 0, 0)

#define MFMA_BF16(a, b, c) __builtin_amdgcn_mfma_f32_16x16x32_bf16((a), (b), (c), 0, 0, 0)

// ---------------------------------------------------------------------------
__global__ void cast_bf16_kernel(const float* __restrict__ x, __bf16* __restrict__ y, int n) {
    int i = (blockIdx.x * blockDim.x + threadIdx.x) * 4;
    if (i < n) {
        float4 v = *reinterpret_cast<const float4*>(x + i);
        bf16x4 o;
        o.x = (__bf16)v.x; o.y = (__bf16)v.y; o.z = (__bf16)v.z; o.w = (__bf16)v.w;
        *reinterpret_cast<bf16x4*>(y + i) = o;
    }
}

// ---------------------------------------------------------------------------
// transpose + cast + scale: W [K][N] fp32 -> WT [N][K] bf16 * scale
// ---------------------------------------------------------------------------
__global__ void transpose_cast_kernel(const float* __restrict__ W, __bf16* __restrict__ WT,
                                      int K, int N, float scale) {
    __shared__ float tile[32][33];
    int bx = blockIdx.x;  // over N/32
    int by = blockIdx.y;  // over K/32
    int tx = threadIdx.x; // 32
    int ty = threadIdx.y; // 8
    int n = bx * 32 + tx;
#pragma unroll
    for (int i = 0; i < 4; i++) {
        int k = by * 32 + ty + i * 8;
        tile[ty + i * 8][tx] = W[(size_t)k * N + n];
    }
    __syncthreads();
    int k2 = by * 32 + tx;
#pragma unroll
    for (int i = 0; i < 4; i++) {
        int n2 = bx * 32 + ty + i * 8;
        WT[(size_t)n2 * K + k2] = (__bf16)(tile[tx][ty + i * 8] * scale);
    }
}

// ---------------------------------------------------------------------------
// strided bf16 transpose: V [R][C] (ld=ldin) -> VT [C][R] (ld=ldout)
// ---------------------------------------------------------------------------
__global__ void transpose_bf16_kernel(const __bf16* __restrict__ V, int ldin,
                                      __bf16* __restrict__ VT, int ldout) {
    __shared__ __bf16 tile[32][33];
    int bx = blockIdx.x;
    int by = blockIdx.y;
    int tx = threadIdx.x;
    int ty = threadIdx.y;
#pragma unroll
    for (int i = 0; i < 4; i++)
        tile[ty + i * 8][tx] = V[(size_t)(by * 32 + ty + i * 8) * ldin + bx * 32 + tx];
    __syncthreads();
#pragma unroll
    for (int i = 0; i < 4; i++)
        VT[(size_t)(bx * 32 + ty + i * 8) * ldout + by * 32 + tx] = tile[tx][ty + i * 8];
}

// ---------------------------------------------------------------------------
// Pipelined NT GEMM, 2-blocks-per-CU variant: C = A[M,K] * BT[N,K]^T.
// Tile BM x BN (BM=128), BK=64; 256 threads = 4 waves (2 x 2); per-wave
// output (BM/2) x (BN/2). Two kk-phases per K-tile.
// Key structural change vs the 256^2 single-block kernel: LDS <= 80 KiB so
// TWO independent blocks co-reside per CU. Blocks don't share barriers, so
// when block A sits in its read/barrier window, block B's waves feed the
// matrix pipe (m114 cross-block overlap) -- the schedule no longer needs to
// hide LDS under MFMA within one block. Grid sized to exactly 2 full
// co-residency rounds (512 blocks) for 100% CU coverage.
// One-phase-ahead ds_read pipeline + T2 source-side XOR swizzle retained.
// ---------------------------------------------------------------------------
template <int BM, int BN, typename OUT_T>
__global__ __launch_bounds__(256, 2) void gemm_pipe2_kernel(const __bf16* __restrict__ A, int lda,
                                                            const __bf16* __restrict__ BT, int ldb,
                                                            OUT_T* __restrict__ C, int ldc, int K) {
    constexpr int NFA = BM / 32;   // A frags per kk per wave
    constexpr int NFB = BN / 32;   // B frags per kk per wave
    constexpr int AR = BM / 32;    // GLD16 staging rounds for A (256 thr)
    constexpr int BR = BN / 32;    // GLD16 staging rounds for B
    __shared__ __bf16 As[2][BM * 64];
    __shared__ __bf16 Bs[2][BN * 64];
    const int n0 = blockIdx.x * BN;
    const int m0 = blockIdx.y * BM;
    const int tid = threadIdx.x;
    const int lane = tid & 63, quad = lane >> 4, l16 = lane & 15;
    const int wave = tid >> 6;
    const int wm = (wave >> 1) * (BM / 2);
    const int wn = (wave & 1) * (BN / 2);

    f32x4 acc[NFA][NFB] = {};

    // stage tile kb into buffer b: source column pre-swizzled (slot ^ row&7)
    auto STAGE = [&](int b, int kb) {
#pragma unroll
        for (int r = 0; r < AR; r++) {
            int c = r * 256 + tid;
            int row = c >> 3;
            int col8 = (c & 7) ^ (row & 7);
            GLD16(&A[(size_t)(m0 + row) * lda + kb + col8 * 8], &As[b][c * 8]);
        }
#pragma unroll
        for (int r = 0; r < BR; r++) {
            int c = r * 256 + tid;
            int row = c >> 3;
            int col8 = (c & 7) ^ (row & 7);
            GLD16(&BT[(size_t)(n0 + row) * ldb + kb + col8 * 8], &Bs[b][c * 8]);
        }
    };

    // issue the ds_reads for one kk-set (NFA+NFB ds_read_b128, swizzled slots)
    auto READ_SET = [&](const __bf16* Asb, const __bf16* Bsb, int kk,
                        bf16x8 (&fa)[NFA], bf16x8 (&fb)[NFB]) {
        int slot = ((kk * 4 + quad) ^ (l16 & 7)) * 8;
#pragma unroll
        for (int i = 0; i < NFA; i++)
            fa[i] = *reinterpret_cast<const bf16x8*>(&Asb[(wm + i * 16 + l16) * 64 + slot]);
#pragma unroll
        for (int j = 0; j < NFB; j++)
            fb[j] = *reinterpret_cast<const bf16x8*>(&Bsb[(wn + j * 16 + l16) * 64 + slot]);
    };

    auto MF = [&](bf16x8 (&fa)[NFA], bf16x8 (&fb)[NFB]) {
        __builtin_amdgcn_s_setprio(1);
#pragma unroll
        for (int i = 0; i < NFA; i++)
#pragma unroll
            for (int j = 0; j < NFB; j++)
                acc[i][j] = MFMA_BF16(fa[i], fb[j], acc[i][j]);
        __builtin_amdgcn_s_setprio(0);
    };

    // wait until only the newest kk-set's reads are outstanding (prev set done)
    auto WAIT_SET = [&]() {
        if constexpr (NFA + NFB == 8) {
            asm volatile("s_waitcnt lgkmcnt(8)" ::: "memory");
        } else if constexpr (NFA + NFB == 10) {
            asm volatile("s_waitcnt lgkmcnt(10)" ::: "memory");
        } else {
            asm volatile("s_waitcnt lgkmcnt(12)" ::: "memory");
        }
        __builtin_amdgcn_sched_barrier(0);
    };

    const int nk = K >> 6;
    bf16x8 fa0[NFA], fb0[NFB], fa1[NFA], fb1[NFB];

    // prologue: stage tiles 0 and 1; wait tile-0 GLDs; barrier -> all landed
    STAGE(0, 0);
    STAGE(1, 64);
    if constexpr (AR + BR == 8) {
        asm volatile("s_waitcnt vmcnt(8)" ::: "memory");
    } else {
        asm volatile("s_waitcnt vmcnt(10)" ::: "memory");
    }
    __builtin_amdgcn_sched_barrier(0);
    __builtin_amdgcn_s_barrier();
    READ_SET(As[0], Bs[0], 0, fa0, fb0);  // kk0 of tile 0 -> set0

    for (int kt = 0; kt < nk; ++kt) {
        const int cur = kt & 1;
        // ---- phase A: compute kk0 (set0), prefetch kk1 (set1) ----
        READ_SET(As[cur], Bs[cur], 1, fa1, fb1);
        WAIT_SET();  // set0 complete (older than the reads just issued)
        MF(fa0, fb0);
        // ---- phase B: compute kk1 (set1), prefetch next tile's kk0 (set0) ----
        if (kt + 1 < nk) {
            asm volatile("s_waitcnt vmcnt(0)" ::: "memory");  // own tile kt+1 GLDs landed
            __builtin_amdgcn_sched_barrier(0);
            __builtin_amdgcn_s_barrier();                     // all waves' tile kt+1 landed
            READ_SET(As[cur ^ 1], Bs[cur ^ 1], 0, fa0, fb0);
            WAIT_SET();  // set1 complete
        } else {
            asm volatile("s_waitcnt lgkmcnt(0)" ::: "memory");
            __builtin_amdgcn_sched_barrier(0);
        }
        if (kt + 2 < nk) {
            __builtin_amdgcn_s_barrier();  // all waves done reading tile kt -> overwrite ok
            STAGE(cur, (kt + 2) << 6);
        }
        MF(fa1, fb1);
    }

#pragma unroll
    for (int i = 0; i < NFA; i++)
#pragma unroll
        for (int j = 0; j < NFB; j++)
#pragma unroll
            for (int r = 0; r < 4; r++) {
                int row = m0 + wm + i * 16 + quad * 4 + r;
                int col = n0 + wn + j * 16 + l16;
                C[(size_t)row * ldc + col] = (OUT_T)acc[i][j][r];
            }
}

// ---------------------------------------------------------------------------
// Flash attention v7 (causal, GQA) — shift-free softmax + MFMA row-sums,
// 2 q-heads per block (K/V staged once serve both), split-KV CS=16.
// ---------------------------------------------------------------------------
__global__ __launch_bounds__(256) void attn_kernel(const __bf16* __restrict__ QKV,
                                                   const __bf16* __restrict__ VT,
                                                   __bf16* __restrict__ Ao,
                                                   __bf16* __restrict__ Opart,
                                                   float* __restrict__ Lp) {
    __shared__ __bf16 Ks[64 * 128];      // K tile [64 kv][128 d], chunk-swizzled
    __shared__ __bf16 Vs[128 * 64];      // V^T tile [128 d][64 kv], chunk-swizzled
    __shared__ __bf16 Pl[4][2][16 * 72]; // per-wave, per-head P buffer (+8 pad)
    int x = blockIdx.x;                  // chunk-slot, heavy-first mapping
    int qt, c;
    if (x < 32) { qt = 31 - (x >> 1); c = x & 1; }   // qt 16..31, 2 chunks
    else        { qt = 47 - x;        c = 0;     }   // qt 15..0, 1 chunk
    int hp = blockIdx.y;                 // head pair 0..15
    int kvh = hp >> 1;
    int h0 = kvh * 4 + (hp & 1) * 2;     // absolute heads h0, h0+1
    int t0 = c ? 16 : 0;
    int t1 = c ? qt : min(qt, 15);
    int tid = threadIdx.x;
    int wave = tid >> 6, lane = tid & 63, quad = lane >> 4, l16 = lane & 15;
    int wq = qt * 64 + wave * 16;        // this wave's 16 q-rows
    const __bf16* Kb = QKV + HID + (size_t)kvh * HD;
    const __bf16* Vt = VT + (size_t)kvh * HD * S_LEN;

    // Q fragments for both heads (pre-scaled by scale*log2e via Wq)
    bf16x8 qf[2][4];
#pragma unroll
    for (int h = 0; h < 2; h++)
#pragma unroll
        for (int ks = 0; ks < 4; ks++)
            qf[h][ks] = *reinterpret_cast<const bf16x8*>(
                &QKV[(size_t)(wq + l16) * LDQKV + (h0 + h) * HD + ks * 32 + quad * 8]);

    bf16x8 ones;
#pragma unroll
    for (int j = 0; j < 8; j++) ones[j] = (__bf16)1.0f;

    f32x4 acc_o[2][8] = {};
    f32x4 lacc[2] = {};

    for (int t = t0; t <= t1; t++) {
        int kv0 = t << 6;
        bool diag = (t == qt);
        __syncthreads();  // previous tile's LDS reads done
        // ---- stage K tile: 1024 chunks of 16B, source-side XOR swizzle
#pragma unroll
        for (int i = 0; i < 4; i++) {
            int cc = i * 256 + tid;
            int row = cc >> 4, sub = cc & 15;
            int col8 = sub ^ (row & 15);
            GLD16(&Kb[(size_t)(kv0 + row) * LDQKV + col8 * 8], &Ks[cc * 8]);
        }
        // ---- stage V^T tile: 1024 chunks of 16B
#pragma unroll
        for (int i = 0; i < 4; i++) {
            int cc = i * 256 + tid;
            int row = cc >> 3, sub = cc & 7;
            int col8 = sub ^ (row & 7);
            GLD16(&Vt[(size_t)row * S_LEN + kv0 + col8 * 8], &Vs[cc * 8]);
        }
        __syncthreads();  // drains vmcnt + barrier

        // ---- S = Q K^T for both heads (kf shared)
        f32x4 sacc[2][4] = {};
#pragma unroll
        for (int ks = 0; ks < 4; ks++) {
            bf16x8 kf[4];
#pragma unroll
            for (int n = 0; n < 4; n++) {
                int row = n * 16 + l16;
                int sub = (ks * 4 + quad) ^ l16;
                kf[n] = *reinterpret_cast<const bf16x8*>(&Ks[row * 128 + sub * 8]);
            }
#pragma unroll
            for (int n = 0; n < 4; n++) {
                sacc[0][n] = MFMA_BF16(qf[0][ks], kf[n], sacc[0][n]);
                sacc[1][n] = MFMA_BF16(qf[1][ks], kf[n], sacc[1][n]);
            }
        }
        // ---- shift-free softmax: P = exp2(S); no reductions at all
#pragma unroll
        for (int h = 0; h < 2; h++) {
            __bf16* Pw = Pl[wave][h];
#pragma unroll
            for (int r = 0; r < 4; r++) {
                int row = wq + quad * 4 + r;
#pragma unroll
                for (int n = 0; n < 4; n++) {
                    float v = sacc[h][n][r];
                    if (diag) {
                        int col = kv0 + n * 16 + l16;
                        if (col > row) v = -1e30f;  // causal mask (diag tile only)
                    }
                    Pw[(quad * 4 + r) * 72 + n * 16 + l16] =
                        (__bf16)__builtin_amdgcn_exp2f(v);
                }
            }
        }
        // ---- O += P V ; l += P * ones (row-sums via MFMA, lands in all lanes)
#pragma unroll
        for (int ks = 0; ks < 2; ks++) {
            bf16x8 pf0 = *reinterpret_cast<const bf16x8*>(
                &Pl[wave][0][l16 * 72 + ks * 32 + quad * 8]);
            bf16x8 pf1 = *reinterpret_cast<const bf16x8*>(
                &Pl[wave][1][l16 * 72 + ks * 32 + quad * 8]);
            lacc[0] = MFMA_BF16(pf0, ones, lacc[0]);
            lacc[1] = MFMA_BF16(pf1, ones, lacc[1]);
#pragma unroll
            for (int dn = 0; dn < 8; dn++) {
                int row = dn * 16 + l16;
                int sub = (ks * 4 + quad) ^ (row & 7);
                bf16x8 vf = *reinterpret_cast<const bf16x8*>(&Vs[row * 64 + sub * 8]);
                acc_o[0][dn] = MFMA_BF16(pf0, vf, acc_o[0][dn]);
                acc_o[1][dn] = MFMA_BF16(pf1, vf, acc_o[1][dn]);
            }
        }
    }

    // ---- epilogue
    if (qt < 16) {
        // single chunk: normalized output
#pragma unroll
        for (int h = 0; h < 2; h++) {
            float rl[4];
#pragma unroll
            for (int r = 0; r < 4; r++) rl[r] = 1.0f / lacc[h][r];
#pragma unroll
            for (int dn = 0; dn < 8; dn++)
#pragma unroll
                for (int r = 0; r < 4; r++) {
                    int row = wq + quad * 4 + r;
                    int col = (h0 + h) * HD + dn * 16 + l16;
                    Ao[(size_t)row * HID + col] = (__bf16)(acc_o[h][dn][r] * rl[r]);
                }
        }
    } else {
        // two-chunk qt: write unnormalized O + l partials
        int s = (qt - 16) * 2 + c;
#pragma unroll
        for (int h = 0; h < 2; h++) {
            size_t base = ((size_t)(h0 + h) * 32 + s) * 64 + wave * 16;
#pragma unroll
            for (int dn = 0; dn < 8; dn++)
#pragma unroll
                for (int r = 0; r < 4; r++)
                    Opart[(base + quad * 4 + r) * 128 + dn * 16 + l16] =
                        (__bf16)acc_o[h][dn][r];
            if (l16 == 0) {
#pragma unroll
                for (int r = 0; r < 4; r++)
                    Lp[base + quad * 4 + r] = lacc[h][r];
            }
        }
    }
}

// ---------------------------------------------------------------------------
// combine two chunks (qt >= 16): O = (O0 + O1) / (l0 + l1). Shift-free, no exp.
// ---------------------------------------------------------------------------
__global__ __launch_bounds__(256) void attn_combine(const __bf16* __restrict__ Opart,
                                                    const float* __restrict__ Lp,
                                                    __bf16* __restrict__ Ao) {
    int qt = 16 + (int)blockIdx.x;  // 16..31
    int h = blockIdx.y;
    int tid = threadIdx.x;
    size_t b0 = ((size_t)h * 32 + (qt - 16) * 2) * 64;
    size_t b1 = b0 + 64;
#pragma unroll 4
    for (int i = 0; i < 32; i++) {
        int el = i * 256 + tid;
        int rl = el >> 7, col = el & 127;
        float l = Lp[b0 + rl] + Lp[b1 + rl];
        float O = (float)Opart[(b0 + rl) * 128 + col] + (float)Opart[(b1 + rl) * 128 + col];
        int row = qt * 64 + rl;
        Ao[(size_t)row * HID + h * HD + col] = (__bf16)(O / l);
    }
}

// ---------------------------------------------------------------------------
extern "C" void kernel_launch(void* const* d_in, const int* in_sizes, int n_in,
                              void* d_out, int out_size, void* d_ws, size_t ws_size,
                              hipStream_t stream) {
    const float* hs = (const float*)d_in[0];
    // d_in[1] = attention_mask (pure causal; applied analytically)
    const float* wq = (const float*)d_in[2];
    const float* wk = (const float*)d_in[3];
    const float* wv = (const float*)d_in[4];
    const float* wo = (const float*)d_in[5];
    float* out = (float*)d_out;

    char* ws = (char*)d_ws;
    // workspace (92 MB with reuse)
    __bf16* WqkvT = (__bf16*)(ws + (size_t)0);          // 48 MB [6144][4096]; reused for WoT
    __bf16* Opart = (__bf16*)(ws + (size_t)0);          // 17 MB attn partials (weight window,
    float*  Lp    = (float*)(ws + ((size_t)20 << 20));  // 0.3 MB  dead during attention)
    __bf16* Xb    = (__bf16*)(ws + ((size_t)48 << 20)); // 16 MB [2048][4096]; reused for attn out
    __bf16* QKV   = (__bf16*)(ws + ((size_t)64 << 20)); // 24 MB [2048][6144]
    __bf16* VTg   = (__bf16*)(ws + ((size_t)88 << 20)); //  4 MB [1024][2048]
    __bf16* Ab    = Xb;

    const int nX = S_LEN * HID;  // 8M
    const float SC2 = 0.12751743f;  // (1/sqrt(128)) * log2(e), folded into Wq

    // 1) cast hidden to bf16
    cast_bf16_kernel<<<nX / 4 / 256, 256, 0, stream>>>(hs, Xb, nX);
    // 2) fused W_{q,k,v}^T (Wq pre-scaled into exp2 domain)
    transpose_cast_kernel<<<dim3(128, 128), dim3(32, 8), 0, stream>>>(wq, WqkvT, HID, HID, SC2);
    transpose_cast_kernel<<<dim3(32, 128), dim3(32, 8), 0, stream>>>(
        wk, WqkvT + (size_t)4096 * HID, HID, NKV * HD, 1.0f);
    transpose_cast_kernel<<<dim3(32, 128), dim3(32, 8), 0, stream>>>(
        wv, WqkvT + (size_t)5120 * HID, HID, NKV * HD, 1.0f);
    // 3) fused QKV GEMM: 128x192 tiles -> 32x16 = 512 blocks, 2 blocks/CU
    gemm_pipe2_kernel<128, 192, __bf16><<<dim3(LDQKV / 192, S_LEN / 128), 256, 0, stream>>>(
        Xb, HID, WqkvT, HID, QKV, LDQKV, HID);
    // 4) V^T for PV B-operand (V = QKV cols 5120..6143)
    transpose_bf16_kernel<<<dim3(32, 64), dim3(32, 8), 0, stream>>>(
        QKV + 5120, LDQKV, VTg, S_LEN);
    // 5) flash attention (2-head blocks, shift-free softmax, split-KV) + combine
    attn_kernel<<<dim3(48, 16), 256, 0, stream>>>(QKV, VTg, Ab, Opart, Lp);
    attn_combine<<<dim3(16, 32), 256, 0, stream>>>(Opart, Lp, Ab);
    // 6) out = Ab @ WoT^T (fp32), 128x128 tiles -> 32x16 = 512 blocks, 2/CU
    transpose_cast_kernel<<<dim3(128, 128), dim3(32, 8), 0, stream>>>(wo, WqkvT, HID, HID, 1.0f);
    gemm_pipe2_kernel<128, 128, float><<<dim3(HID / 128, S_LEN / 128), 256, 0, stream>>>(
        Ab, HID, WqkvT, HID, out, HID, HID);
}